// Round 10
// baseline (140.028 us; speedup 1.0000x reference)
//
#include <hip/hip_runtime.h>
#include <math.h>

#define FIN   64
#define NK    512
#define FOUT  256
#define BB    16
#define NTHR  1024
#define RSTRH 520   // ushort stride: 1040B row = 65*16B; uniform bank coverage for b128

typedef __attribute__((ext_vector_type(8))) short short8;
typedef __attribute__((ext_vector_type(4))) float f32x4;
typedef unsigned short ushort_t;

#define MFMA(a, b, c) __builtin_amdgcn_mfma_f32_16x16x32_bf16((a), (b), (c), 0, 0, 0)

// ---- ws layout (ushort element offsets; all 16B-aligned) ----
#define XHI   0
#define XMID  262144
#define XLO   524288
#define CHI   786432
#define CMID  819200
#define CLO   851968
#define WHI   884736
#define WLO   1015808
#define USH_END 1146880          // *2B = 2,293,760 B (16B-aligned)
// float section (fs = (float*)(us + USH_END)):
#define CSQ_F 0
#define E2_F  512
#define XSQ_F 1024               // 4096 entries

__device__ __forceinline__ ushort_t top16(float f) {
    return (ushort_t)(__builtin_bit_cast(unsigned, f) >> 16);
}
__device__ __forceinline__ float trunc_bf(float f) {
    return __builtin_bit_cast(float, __builtin_bit_cast(unsigned, f) & 0xFFFF0000u);
}

// ---------------- prep: all conversions, once per launch ----------------
__global__ __launch_bounds__(256) void rbf_prep_kernel(
    const float* __restrict__ x, const float* __restrict__ w,
    const float* __restrict__ cent, const float* __restrict__ ls,
    ushort_t* __restrict__ us, float* __restrict__ fs)
{
    const int gid = blockIdx.x * 256 + threadIdx.x;
    const int nth = gridDim.x * 256;

    for (int i = gid; i < 4096 * FIN; i += nth) {        // x: 3-split
        const float v = x[i];
        const float m1 = v - trunc_bf(v);
        const float l1 = m1 - trunc_bf(m1);
        us[XHI + i]  = top16(v);
        us[XMID + i] = top16(m1);
        us[XLO + i]  = top16(l1);
    }
    for (int i = gid; i < NK * FIN; i += nth) {          // cent: 3-split
        const float v = cent[i];
        const float m1 = v - trunc_bf(v);
        const float l1 = m1 - trunc_bf(m1);
        us[CHI + i]  = top16(v);
        us[CMID + i] = top16(m1);
        us[CLO + i]  = top16(l1);
    }
    for (int i = gid; i < FOUT * NK; i += nth) {         // w: 2-split
        const float v = w[i];
        const float l1 = v - trunc_bf(v);
        us[WHI + i] = top16(v);
        us[WLO + i] = top16(l1);
    }
    for (int r = gid; r < 4096; r += nth) {              // xsq (exact f32)
        const float4* xp = (const float4*)(x + (size_t)r * FIN);
        float s = 0.f;
        #pragma unroll
        for (int j = 0; j < 16; ++j) {
            const float4 c = xp[j];
            s = fmaf(c.x, c.x, s); s = fmaf(c.y, c.y, s);
            s = fmaf(c.z, c.z, s); s = fmaf(c.w, c.w, s);
        }
        fs[XSQ_F + r] = s;
    }
    for (int k = gid; k < NK; k += nth) {                // csq + e2
        const float4* cp = (const float4*)(cent + (size_t)k * FIN);
        float s = 0.f;
        #pragma unroll
        for (int j = 0; j < 16; ++j) {
            const float4 c = cp[j];
            s = fmaf(c.x, c.x, s); s = fmaf(c.y, c.y, s);
            s = fmaf(c.z, c.z, s); s = fmaf(c.w, c.w, s);
        }
        fs[CSQ_F + k] = s;
        fs[E2_F + k]  = __expf(2.f * ls[k]);
    }
}

// ---------------- main: ILP-restructured, idempotent ----------------
__global__ __launch_bounds__(NTHR, 1) void rbf_main_kernel(
    const ushort_t* __restrict__ us, const float* __restrict__ fs,
    float* __restrict__ out)
{
    __shared__ __align__(16) ushort_t RsHi[BB][RSTRH];   // 16.6 KB
    __shared__ __align__(16) ushort_t RsLo[BB][RSTRH];   // 16.6 KB
    __shared__ float rowpart[16][BB];
    __shared__ float invs[BB];

    const int tid   = threadIdx.x;
    const int lane  = tid & 63;
    const int wv    = tid >> 6;       // 0..15
    const int arow  = lane & 15;
    const int dg    = lane >> 4;      // 0..3
    const int d0    = dg * 8;
    const int rbase = dg * 4;
    const int b0    = blockIdx.x * BB;

    // A-fragments: pre-split x
    const int xoff = (b0 + arow) * FIN;
    const short8 ax1_0 = *(const short8*)&us[XHI  + xoff + d0];
    const short8 ax1_1 = *(const short8*)&us[XHI  + xoff + 32 + d0];
    const short8 ax2_0 = *(const short8*)&us[XMID + xoff + d0];
    const short8 ax2_1 = *(const short8*)&us[XMID + xoff + 32 + d0];
    const short8 ax3_0 = *(const short8*)&us[XLO  + xoff + d0];
    const short8 ax3_1 = *(const short8*)&us[XLO  + xoff + 32 + d0];

    const float xq0 = fs[XSQ_F + b0 + rbase + 0];
    const float xq1 = fs[XSQ_F + b0 + rbase + 1];
    const float xq2 = fs[XSQ_F + b0 + rbase + 2];
    const float xq3 = fs[XSQ_F + b0 + rbase + 3];

    // ---- phase 2: both 16-col tiles unrolled, 2 independent MFMA chains ----
    const int colA  = 32 * wv + arow;
    const int colB  = colA + 16;
    const int cofA  = colA * FIN;
    const int cofB  = colB * FIN;

    const short8 bA1_0 = *(const short8*)&us[CHI  + cofA + d0];
    const short8 bA1_1 = *(const short8*)&us[CHI  + cofA + 32 + d0];
    const short8 bA2_0 = *(const short8*)&us[CMID + cofA + d0];
    const short8 bA2_1 = *(const short8*)&us[CMID + cofA + 32 + d0];
    const short8 bA3_0 = *(const short8*)&us[CLO  + cofA + d0];
    const short8 bA3_1 = *(const short8*)&us[CLO  + cofA + 32 + d0];
    const short8 bB1_0 = *(const short8*)&us[CHI  + cofB + d0];
    const short8 bB1_1 = *(const short8*)&us[CHI  + cofB + 32 + d0];
    const short8 bB2_0 = *(const short8*)&us[CMID + cofB + d0];
    const short8 bB2_1 = *(const short8*)&us[CMID + cofB + 32 + d0];
    const short8 bB3_0 = *(const short8*)&us[CLO  + cofB + d0];
    const short8 bB3_1 = *(const short8*)&us[CLO  + cofB + 32 + d0];

    f32x4 accA = {0.f, 0.f, 0.f, 0.f};
    f32x4 accB = {0.f, 0.f, 0.f, 0.f};
    accA = MFMA(ax1_0, bA1_0, accA);  accB = MFMA(ax1_0, bB1_0, accB);
    accA = MFMA(ax1_0, bA2_0, accA);  accB = MFMA(ax1_0, bB2_0, accB);
    accA = MFMA(ax2_0, bA1_0, accA);  accB = MFMA(ax2_0, bB1_0, accB);
    accA = MFMA(ax2_0, bA2_0, accA);  accB = MFMA(ax2_0, bB2_0, accB);
    accA = MFMA(ax1_0, bA3_0, accA);  accB = MFMA(ax1_0, bB3_0, accB);
    accA = MFMA(ax3_0, bA1_0, accA);  accB = MFMA(ax3_0, bB1_0, accB);
    accA = MFMA(ax1_1, bA1_1, accA);  accB = MFMA(ax1_1, bB1_1, accB);
    accA = MFMA(ax1_1, bA2_1, accA);  accB = MFMA(ax1_1, bB2_1, accB);
    accA = MFMA(ax2_1, bA1_1, accA);  accB = MFMA(ax2_1, bB1_1, accB);
    accA = MFMA(ax2_1, bA2_1, accA);  accB = MFMA(ax2_1, bB2_1, accB);
    accA = MFMA(ax1_1, bA3_1, accA);  accB = MFMA(ax1_1, bB3_1, accB);
    accA = MFMA(ax3_1, bA1_1, accA);  accB = MFMA(ax3_1, bB1_1, accB);

    float ps0 = 0.f, ps1 = 0.f, ps2 = 0.f, ps3 = 0.f;
    {
        const float cqA = fs[CSQ_F + colA], e2A = fs[E2_F + colA];
        const float cqB = fs[CSQ_F + colB], e2B = fs[E2_F + colB];
        float rb;
        rb = __expf(-(e2A * fmaf(-2.f, accA[0], xq0 + cqA)));
        ps0 += rb; RsHi[rbase + 0][colA] = top16(rb); RsLo[rbase + 0][colA] = top16(rb - trunc_bf(rb));
        rb = __expf(-(e2A * fmaf(-2.f, accA[1], xq1 + cqA)));
        ps1 += rb; RsHi[rbase + 1][colA] = top16(rb); RsLo[rbase + 1][colA] = top16(rb - trunc_bf(rb));
        rb = __expf(-(e2A * fmaf(-2.f, accA[2], xq2 + cqA)));
        ps2 += rb; RsHi[rbase + 2][colA] = top16(rb); RsLo[rbase + 2][colA] = top16(rb - trunc_bf(rb));
        rb = __expf(-(e2A * fmaf(-2.f, accA[3], xq3 + cqA)));
        ps3 += rb; RsHi[rbase + 3][colA] = top16(rb); RsLo[rbase + 3][colA] = top16(rb - trunc_bf(rb));
        rb = __expf(-(e2B * fmaf(-2.f, accB[0], xq0 + cqB)));
        ps0 += rb; RsHi[rbase + 0][colB] = top16(rb); RsLo[rbase + 0][colB] = top16(rb - trunc_bf(rb));
        rb = __expf(-(e2B * fmaf(-2.f, accB[1], xq1 + cqB)));
        ps1 += rb; RsHi[rbase + 1][colB] = top16(rb); RsLo[rbase + 1][colB] = top16(rb - trunc_bf(rb));
        rb = __expf(-(e2B * fmaf(-2.f, accB[2], xq2 + cqB)));
        ps2 += rb; RsHi[rbase + 2][colB] = top16(rb); RsLo[rbase + 2][colB] = top16(rb - trunc_bf(rb));
        rb = __expf(-(e2B * fmaf(-2.f, accB[3], xq3 + cqB)));
        ps3 += rb; RsHi[rbase + 3][colB] = top16(rb); RsLo[rbase + 3][colB] = top16(rb - trunc_bf(rb));
    }
    ps0 += __shfl_xor(ps0, 1); ps0 += __shfl_xor(ps0, 2); ps0 += __shfl_xor(ps0, 4); ps0 += __shfl_xor(ps0, 8);
    ps1 += __shfl_xor(ps1, 1); ps1 += __shfl_xor(ps1, 2); ps1 += __shfl_xor(ps1, 4); ps1 += __shfl_xor(ps1, 8);
    ps2 += __shfl_xor(ps2, 1); ps2 += __shfl_xor(ps2, 2); ps2 += __shfl_xor(ps2, 4); ps2 += __shfl_xor(ps2, 8);
    ps3 += __shfl_xor(ps3, 1); ps3 += __shfl_xor(ps3, 2); ps3 += __shfl_xor(ps3, 4); ps3 += __shfl_xor(ps3, 8);
    if (arow == 0) {
        rowpart[wv][rbase + 0] = ps0;
        rowpart[wv][rbase + 1] = ps1;
        rowpart[wv][rbase + 2] = ps2;
        rowpart[wv][rbase + 3] = ps3;
    }
    __syncthreads();
    if (tid < BB) {
        float s = 0.f;
        #pragma unroll
        for (int q = 0; q < 16; ++q) s += rowpart[q][tid];
        invs[tid] = 1.f / (1e-9f + s);
    }
    __syncthreads();

    // ---- phase 4: out = R W^T, two independent chains (even/odd ks) ----
    const int c0 = 16 * wv;
    const int w0off = (c0 + arow) * NK;

    f32x4 oA = {0.f, 0.f, 0.f, 0.f};
    f32x4 oB = {0.f, 0.f, 0.f, 0.f};
    #pragma unroll 4
    for (int kp = 0; kp < NK / 64; ++kp) {
        const int kbA = kp * 64 + d0;
        const int kbB = kbA + 32;
        const short8 ahiA = *(const short8*)&RsHi[arow][kbA];
        const short8 aloA = *(const short8*)&RsLo[arow][kbA];
        const short8 whA  = *(const short8*)&us[WHI + w0off + kbA];
        const short8 wlA  = *(const short8*)&us[WLO + w0off + kbA];
        const short8 ahiB = *(const short8*)&RsHi[arow][kbB];
        const short8 aloB = *(const short8*)&RsLo[arow][kbB];
        const short8 whB  = *(const short8*)&us[WHI + w0off + kbB];
        const short8 wlB  = *(const short8*)&us[WLO + w0off + kbB];
        oA = MFMA(ahiA, whA, oA);  oB = MFMA(ahiB, whB, oB);
        oA = MFMA(ahiA, wlA, oA);  oB = MFMA(ahiB, wlB, oB);
        oA = MFMA(aloA, whA, oA);  oB = MFMA(aloB, whB, oB);
    }
    const f32x4 o0 = oA + oB;

    #pragma unroll
    for (int j = 0; j < 4; ++j) {
        const int row = rbase + j;
        out[(size_t)(b0 + row) * FOUT + c0 + arow] = o0[j] * invs[row];
    }
}

extern "C" void kernel_launch(void* const* d_in, const int* in_sizes, int n_in,
                              void* d_out, int out_size, void* d_ws, size_t ws_size,
                              hipStream_t stream) {
    const float* x    = (const float*)d_in[0];   // [4096][64]
    const float* w    = (const float*)d_in[1];   // [256][512]
    const float* cent = (const float*)d_in[2];   // [512][64]
    const float* ls   = (const float*)d_in[3];   // [512]
    float* out        = (float*)d_out;           // [4096][256]

    ushort_t* us = (ushort_t*)d_ws;
    float*    fs = (float*)(us + USH_END);

    rbf_prep_kernel<<<dim3(1024), dim3(256), 0, stream>>>(x, w, cent, ls, us, fs);
    // PROBE: main is idempotent; 3x launch measures its true cost via
    // dur_us delta (rocprof top-5 is crowded out by the 41us ws-poison fills).
    rbf_main_kernel<<<dim3(4096 / BB), dim3(NTHR), 0, stream>>>(us, fs, out);
    rbf_main_kernel<<<dim3(4096 / BB), dim3(NTHR), 0, stream>>>(us, fs, out);
    rbf_main_kernel<<<dim3(4096 / BB), dim3(NTHR), 0, stream>>>(us, fs, out);
}

// Round 12
// 98.253 us; speedup vs baseline: 1.4252x; 1.4252x over previous
//
#include <hip/hip_runtime.h>
#include <math.h>

#define FIN   64
#define NK    512
#define FOUT  256
#define BB    32
#define NTHR  1024
#define RSTRH 520   // ushort stride: 1040B row; full-wave b128 is at the structural LDS floor

typedef __attribute__((ext_vector_type(8))) short short8;
typedef __attribute__((ext_vector_type(8))) unsigned short ushort8;
typedef __attribute__((ext_vector_type(4))) float f32x4;
typedef unsigned short ushort_t;

#define MFMA(a, b, c) __builtin_amdgcn_mfma_f32_16x16x32_bf16((a), (b), (c), 0, 0, 0)

// ---- ws layout (ushort element offsets; all 16B-aligned) ----
#define XHI   0
#define XMID  262144
#define XLO   524288
#define CHI   786432
#define CMID  819200
#define CLO   851968
#define WHI   884736
#define WLO   1015808
#define USH_END 1146880          // *2B = 2,293,760 B
// float section (fs = (float*)(us + USH_END)):
#define CSQ_F 0
#define E2_F  512
#define XSQ_F 1024               // 4096 entries

__device__ __forceinline__ ushort_t top16(float f) {
    return (ushort_t)(__builtin_bit_cast(unsigned, f) >> 16);
}
__device__ __forceinline__ float trunc_bf(float f) {
    return __builtin_bit_cast(float, __builtin_bit_cast(unsigned, f) & 0xFFFF0000u);
}

union U8 { ushort_t a[8]; ushort8 v; };

// ---------------- prep: vectorized conversions (16B stores) ----------------
__global__ __launch_bounds__(256) void rbf_prep_kernel(
    const float* __restrict__ x, const float* __restrict__ w,
    const float* __restrict__ cent, const float* __restrict__ ls,
    ushort_t* __restrict__ us, float* __restrict__ fs)
{
    const int gid = blockIdx.x * 256 + threadIdx.x;
    const int nth = gridDim.x * 256;

    for (int t = gid; t < 4096 * FIN / 8; t += nth) {    // x: 3-split, 8/thread
        const int i = t * 8;
        const float4 a = *(const float4*)(x + i);
        const float4 b = *(const float4*)(x + i + 4);
        const float f[8] = {a.x, a.y, a.z, a.w, b.x, b.y, b.z, b.w};
        U8 H, M, L;
        #pragma unroll
        for (int j = 0; j < 8; ++j) {
            const float v  = f[j];
            const float m1 = v - trunc_bf(v);
            const float l1 = m1 - trunc_bf(m1);
            H.a[j] = top16(v);
            M.a[j] = top16(m1);
            L.a[j] = top16(l1);
        }
        *(ushort8*)&us[XHI + i]  = H.v;
        *(ushort8*)&us[XMID + i] = M.v;
        *(ushort8*)&us[XLO + i]  = L.v;
    }
    for (int t = gid; t < NK * FIN / 8; t += nth) {      // cent: 3-split
        const int i = t * 8;
        const float4 a = *(const float4*)(cent + i);
        const float4 b = *(const float4*)(cent + i + 4);
        const float f[8] = {a.x, a.y, a.z, a.w, b.x, b.y, b.z, b.w};
        U8 H, M, L;
        #pragma unroll
        for (int j = 0; j < 8; ++j) {
            const float v  = f[j];
            const float m1 = v - trunc_bf(v);
            const float l1 = m1 - trunc_bf(m1);
            H.a[j] = top16(v);
            M.a[j] = top16(m1);
            L.a[j] = top16(l1);
        }
        *(ushort8*)&us[CHI + i]  = H.v;
        *(ushort8*)&us[CMID + i] = M.v;
        *(ushort8*)&us[CLO + i]  = L.v;
    }
    for (int t = gid; t < FOUT * NK / 8; t += nth) {     // w: 2-split
        const int i = t * 8;
        const float4 a = *(const float4*)(w + i);
        const float4 b = *(const float4*)(w + i + 4);
        const float f[8] = {a.x, a.y, a.z, a.w, b.x, b.y, b.z, b.w};
        U8 H, L;
        #pragma unroll
        for (int j = 0; j < 8; ++j) {
            const float v = f[j];
            H.a[j] = top16(v);
            L.a[j] = top16(v - trunc_bf(v));
        }
        *(ushort8*)&us[WHI + i] = H.v;
        *(ushort8*)&us[WLO + i] = L.v;
    }
    for (int r = gid; r < 4096; r += nth) {              // xsq (exact f32)
        const float4* xp = (const float4*)(x + (size_t)r * FIN);
        float s = 0.f;
        #pragma unroll
        for (int j = 0; j < 16; ++j) {
            const float4 c = xp[j];
            s = fmaf(c.x, c.x, s); s = fmaf(c.y, c.y, s);
            s = fmaf(c.z, c.z, s); s = fmaf(c.w, c.w, s);
        }
        fs[XSQ_F + r] = s;
    }
    for (int k = gid; k < NK; k += nth) {                // csq + e2
        const float4* cp = (const float4*)(cent + (size_t)k * FIN);
        float s = 0.f;
        #pragma unroll
        for (int j = 0; j < 16; ++j) {
            const float4 c = cp[j];
            s = fmaf(c.x, c.x, s); s = fmaf(c.y, c.y, s);
            s = fmaf(c.z, c.z, s); s = fmaf(c.w, c.w, s);
        }
        fs[CSQ_F + k] = s;
        fs[E2_F + k]  = __expf(2.f * ls[k]);
    }
}

// ---------------- main: BB=32, cent/W fragments reused across row-groups ----------------
__global__ __launch_bounds__(NTHR, 1) void rbf_main_kernel(
    const ushort_t* __restrict__ us, const float* __restrict__ fs,
    float* __restrict__ out)
{
    __shared__ __align__(16) ushort_t RsHi[BB][RSTRH];   // 33.3 KB
    __shared__ __align__(16) ushort_t RsLo[BB][RSTRH];   // 33.3 KB
    __shared__ float rowpart[16][BB];                    // 2 KB
    __shared__ float invs[BB];

    const int tid   = threadIdx.x;
    const int lane  = tid & 63;
    const int wv    = tid >> 6;       // 0..15
    const int arow  = lane & 15;
    const int dg    = lane >> 4;      // 0..3
    const int d0    = dg * 8;
    const int rbase = dg * 4;
    const int b0    = blockIdx.x * BB;

    // hoisted xsq for my 8 output rows (2 row-groups x 4)
    float xq[8];
    #pragma unroll
    for (int rg = 0; rg < 2; ++rg)
        #pragma unroll
        for (int j = 0; j < 4; ++j)
            xq[rg * 4 + j] = fs[XSQ_F + b0 + rg * 16 + rbase + j];

    // ---- phase 2: cross = X C^T (3-split MFMA); B-frags loaded once per col-tile,
    //      reused for both row-groups ----
    float ps[8];
    #pragma unroll
    for (int q = 0; q < 8; ++q) ps[q] = 0.f;

    #pragma unroll
    for (int ct = 0; ct < 2; ++ct) {
        const int col  = 32 * wv + 16 * ct + arow;
        const int coff = col * FIN;
        const short8 b1_0 = *(const short8*)&us[CHI  + coff + d0];
        const short8 b1_1 = *(const short8*)&us[CHI  + coff + 32 + d0];
        const short8 b2_0 = *(const short8*)&us[CMID + coff + d0];
        const short8 b2_1 = *(const short8*)&us[CMID + coff + 32 + d0];
        const short8 b3_0 = *(const short8*)&us[CLO  + coff + d0];
        const short8 b3_1 = *(const short8*)&us[CLO  + coff + 32 + d0];
        const float cq = fs[CSQ_F + col];
        const float e2 = fs[E2_F + col];

        #pragma unroll
        for (int rg = 0; rg < 2; ++rg) {
            const int xoff = (b0 + rg * 16 + arow) * FIN;
            const short8 a1_0 = *(const short8*)&us[XHI  + xoff + d0];
            const short8 a1_1 = *(const short8*)&us[XHI  + xoff + 32 + d0];
            const short8 a2_0 = *(const short8*)&us[XMID + xoff + d0];
            const short8 a2_1 = *(const short8*)&us[XMID + xoff + 32 + d0];
            const short8 a3_0 = *(const short8*)&us[XLO  + xoff + d0];
            const short8 a3_1 = *(const short8*)&us[XLO  + xoff + 32 + d0];

            f32x4 acc = {0.f, 0.f, 0.f, 0.f};
            acc = MFMA(a1_0, b1_0, acc);
            acc = MFMA(a1_0, b2_0, acc);
            acc = MFMA(a2_0, b1_0, acc);
            acc = MFMA(a2_0, b2_0, acc);
            acc = MFMA(a1_0, b3_0, acc);
            acc = MFMA(a3_0, b1_0, acc);
            acc = MFMA(a1_1, b1_1, acc);
            acc = MFMA(a1_1, b2_1, acc);
            acc = MFMA(a2_1, b1_1, acc);
            acc = MFMA(a2_1, b2_1, acc);
            acc = MFMA(a1_1, b3_1, acc);
            acc = MFMA(a3_1, b1_1, acc);

            // C layout: col=lane&15, row=(lane>>4)*4+j  [verified m89/m91]
            #pragma unroll
            for (int j = 0; j < 4; ++j) {
                const int rl = rg * 16 + rbase + j;
                const float ssq = fmaf(-2.f, acc[j], xq[rg * 4 + j] + cq);
                const float rb  = __expf(-(e2 * ssq));
                ps[rg * 4 + j] += rb;
                RsHi[rl][col] = top16(rb);
                RsLo[rl][col] = top16(rb - trunc_bf(rb));
            }
        }
    }
    // fold row partials across the 16 n-lanes
    #pragma unroll
    for (int q = 0; q < 8; ++q) {
        ps[q] += __shfl_xor(ps[q], 1);
        ps[q] += __shfl_xor(ps[q], 2);
        ps[q] += __shfl_xor(ps[q], 4);
        ps[q] += __shfl_xor(ps[q], 8);
    }
    if (arow == 0) {
        #pragma unroll
        for (int rg = 0; rg < 2; ++rg)
            #pragma unroll
            for (int j = 0; j < 4; ++j)
                rowpart[wv][rg * 16 + rbase + j] = ps[rg * 4 + j];
    }
    __syncthreads();
    if (tid < BB) {
        float s = 0.f;
        #pragma unroll
        for (int q = 0; q < 16; ++q) s += rowpart[q][tid];
        invs[tid] = 1.f / (1e-9f + s);
    }
    __syncthreads();

    // ---- phase 4: out = R W^T (2-split MFMA); W-frags reused across row-groups ----
    const int c0   = 16 * wv;
    const int woff = (c0 + arow) * NK;

    f32x4 o0 = {0.f, 0.f, 0.f, 0.f};
    f32x4 o1 = {0.f, 0.f, 0.f, 0.f};
    #pragma unroll 4
    for (int kp = 0; kp < NK / 32; ++kp) {
        const int kb = kp * 32 + d0;
        const short8 wh   = *(const short8*)&us[WHI + woff + kb];
        const short8 wl   = *(const short8*)&us[WLO + woff + kb];
        const short8 ahi0 = *(const short8*)&RsHi[arow][kb];
        const short8 alo0 = *(const short8*)&RsLo[arow][kb];
        const short8 ahi1 = *(const short8*)&RsHi[16 + arow][kb];
        const short8 alo1 = *(const short8*)&RsLo[16 + arow][kb];
        o0 = MFMA(ahi0, wh, o0);  o1 = MFMA(ahi1, wh, o1);
        o0 = MFMA(ahi0, wl, o0);  o1 = MFMA(ahi1, wl, o1);
        o0 = MFMA(alo0, wh, o0);  o1 = MFMA(alo1, wh, o1);
    }

    // ---- epilogue ----
    #pragma unroll
    for (int j = 0; j < 4; ++j) {
        const int r0 = rbase + j;
        out[(size_t)(b0 + r0) * FOUT + c0 + arow] = o0[j] * invs[r0];
    }
    #pragma unroll
    for (int j = 0; j < 4; ++j) {
        const int r1 = 16 + rbase + j;
        out[(size_t)(b0 + r1) * FOUT + c0 + arow] = o1[j] * invs[r1];
    }
}

extern "C" void kernel_launch(void* const* d_in, const int* in_sizes, int n_in,
                              void* d_out, int out_size, void* d_ws, size_t ws_size,
                              hipStream_t stream) {
    const float* x    = (const float*)d_in[0];   // [4096][64]
    const float* w    = (const float*)d_in[1];   // [256][512]
    const float* cent = (const float*)d_in[2];   // [512][64]
    const float* ls   = (const float*)d_in[3];   // [512]
    float* out        = (float*)d_out;           // [4096][256]

    ushort_t* us = (ushort_t*)d_ws;
    float*    fs = (float*)(us + USH_END);

    rbf_prep_kernel<<<dim3(256), dim3(256), 0, stream>>>(x, w, cent, ls, us, fs);
    rbf_main_kernel<<<dim3(4096 / BB), dim3(NTHR), 0, stream>>>(us, fs, out);
}